// Round 12
// baseline (328.731 us; speedup 1.0000x reference)
//
#include <hip/hip_runtime.h>
#include <hip/hip_bf16.h>
#include <stdint.h>

// EdgeDecoder: out = relu(concat(zd[row], zt[col]) @ W1 + b1) @ W2 + b2
// R14 = R13's U/V-split + row-sorted gather, with the sort made cheap and
// the gather pass fixed:
//  - hist fused into prep (64 extra blocks, LDS-hist -> private bins2d rows,
//    no atomics, no memset); 1-block scan; scatter is the only atomic pass.
//  - perm packed as int4{row,col,e}: edge pass reads ONE sequential 16B
//    record; no random row[pe]/col[pe] 4B gathers (~60MB fills saved).
//  - edge pass: contiguous 256-edge block ranges + bijective XCD swizzle
//    (m204) so each XCD's U slab (~3.2MB) lives in its private 4MB L2.
//  - uv_gemm reverted to R12-exact (known-good ~55us; R13's full-width
//    variant was an uncontrolled change).

typedef unsigned short u16;
typedef __attribute__((ext_vector_type(8))) short short8;
typedef __attribute__((ext_vector_type(4))) float f32x4;

#define HDIM 256
#define KDIM 512
#define BK 64
#define BIN_SHIFT 4
#define NHIST 64

__device__ __forceinline__ u16 f2bf(float f) {
  union { float f; uint32_t u; } v; v.f = f;
  uint32_t u = v.u;
  return (u16)((u + 0x7fffu + ((u >> 16) & 1u)) >> 16);   // RNE, inputs finite
}
__device__ __forceinline__ u16 f2h(float f) {
  union { _Float16 h; u16 u; } v; v.h = (_Float16)f;      // v_cvt_f16_f32 RNE
  return v.u;
}
__device__ __forceinline__ float h2f(u16 b) {
  union { _Float16 h; u16 u; } v; v.u = b;
  return (float)v.h;
}

// async global->LDS, 16B per lane; LDS dest must be wave-uniform base (+lane*16)
__device__ __forceinline__ void gl2lds16(const void* g, void* l) {
  __builtin_amdgcn_global_load_lds(
      (const __attribute__((address_space(1))) unsigned int*)g,
      (__attribute__((address_space(3))) unsigned int*)l,
      16, 0, 0);
}

// Prep + hist: blocks 0..31 transpose W1 (512x256 fp32 -> 256x512 bf16);
// blocks 32..95 build private histogram rows of row>>BIN_SHIFT (no atomics).
__global__ void prep_hist(const float* __restrict__ w1, u16* __restrict__ w1t,
                          const int* __restrict__ row, int* __restrict__ bins2d,
                          int E, int NB) {
  const int b = blockIdx.x;
  __shared__ float tile[64][65];
  __shared__ int lh[3200];
  if (b < 32) {
    const int k0 = (b >> 2) * 64, n0 = (b & 3) * 64;
    const int tx = threadIdx.x & 63, ty = threadIdx.x >> 6;
#pragma unroll
    for (int i = ty; i < 64; i += 4)
      tile[i][tx] = w1[(size_t)(k0 + i) * HDIM + n0 + tx];
    __syncthreads();
#pragma unroll
    for (int i = ty; i < 64; i += 4)
      w1t[(size_t)(n0 + i) * KDIM + k0 + tx] = f2bf(tile[tx][i]);
  } else {
    const int hb = b - 32;                       // 0..NHIST-1
    for (int i = threadIdx.x; i < NB; i += 256) lh[i] = 0;
    __syncthreads();
    for (int e = hb * 256 + threadIdx.x; e < E; e += NHIST * 256)
      atomicAdd(&lh[row[e] >> BIN_SHIFT], 1);    // LDS atomics (fast)
    __syncthreads();
    for (int i = threadIdx.x; i < NB; i += 256)
      bins2d[(size_t)hb * NB + i] = lh[i];       // private row, no atomics
  }
}

// Scan: one block; tot[i] = sum_b bins2d[b][i]; cursor = exclusive prefix.
__global__ void scan_kernel(const int* __restrict__ bins2d,
                            int* __restrict__ cursor, int NB) {
  __shared__ int part[256];
  const int t = threadIdx.x;
  const int per = (NB + 255) / 256;
  const int lo = t * per, hi = min(lo + per, NB);
  int s = 0;
  for (int i = lo; i < hi; ++i) {
    int tot = 0;
#pragma unroll 4
    for (int b = 0; b < NHIST; ++b) tot += bins2d[(size_t)b * NB + i];
    cursor[i] = tot;                             // stash totals
    s += tot;
  }
  part[t] = s;
  __syncthreads();
  if (t == 0) {
    int a = 0;
    for (int i = 0; i < 256; ++i) { int c = part[i]; part[i] = a; a += c; }
  }
  __syncthreads();
  int run = part[t];
  for (int i = lo; i < hi; ++i) { int c = cursor[i]; cursor[i] = run; run += c; }
}

// Scatter: the only global-atomic pass. Packs {row, col, e} per sorted slot.
__global__ void scatter_kernel(const int* __restrict__ row,
                               const int* __restrict__ col,
                               int* __restrict__ cursor,
                               int4* __restrict__ perm4, int E) {
  for (int e = blockIdx.x * 256 + threadIdx.x; e < E; e += gridDim.x * 256) {
    int r = row[e];
    int pos = atomicAdd(&cursor[r >> BIN_SHIFT], 1);
    perm4[pos] = make_int4(r, col[e], e, 0);
  }
}

// UV GEMM (R12-exact): blocks [0,nUb) U = zd @ W1d (+b1 folded), rest
// V = zt @ W1t. Block = 128 rows x 128 cols, wave = 32 rows x 128 cols,
// acc[2][8]; A from fp32 z rows cvt in-reg (dbuf); B gl2lds+XOR-swizzle.
__global__ __launch_bounds__(256, 2) void uv_gemm(
    const float* __restrict__ zdf, const float* __restrict__ ztf,
    const u16* __restrict__ w1t, const float* __restrict__ b1,
    u16* __restrict__ Uh, u16* __restrict__ Vh,
    int ND, int NT, int nUb) {
  __shared__ u16 lB[2][128 * BK];   // 2 x 16KB [n_local][k], XOR-swizzled

  const int bid = blockIdx.x;
  const int isV = (bid >= nUb);
  const int lb  = isV ? (bid - nUb) : bid;
  const float* zf = isV ? ztf : zdf;
  u16* Oh = isV ? Vh : Uh;
  const int NR = isV ? NT : ND;
  const int r0 = (lb >> 1) * 128;
  const int n0 = (lb & 1) * 128;
  const int kb = isV ? 4 : 0;       // k-chunk base into W1T's 512-k dim

  const int tid   = threadIdx.x;
  const int wid   = tid >> 6;
  const int lane  = tid & 63;
  const int r8    = lane >> 3;
  const int slog  = ((lane & 7) ^ (r8 & 7)) * 8;   // inv-swizzled src piece
  const int colid = lane & 15;
  const int quad  = lane >> 4;
  const int csw   = colid & 7;

  const u16* pB = w1t + (uint32_t)(n0 + wid * 32 + r8) * KDIM + slog;
  u16* lBw0 = &lB[0][(wid * 32) * BK];
  u16* lBw1 = &lB[1][(wid * 32) * BK];

  uint32_t offR[2];
#pragma unroll
  for (int rt = 0; rt < 2; ++rt) {
    int r = min(r0 + wid * 32 + rt * 16 + colid, NR - 1);
    offR[rt] = (uint32_t)r * HDIM;
  }

  f32x4 acc[2][8];
#pragma unroll
  for (int i = 0; i < 2; ++i)
#pragma unroll
    for (int j = 0; j < 8; ++j) acc[i][j] = f32x4{0.f, 0.f, 0.f, 0.f};

  float4 a32[2][2][2][2];  // [buf][rt][s][half] in-flight fp32 A
  short8 aB[2][2][2];      // [buf][rt][s] bf16 fragments

  auto loadA = [&](int kc, int buf) {
#pragma unroll
    for (int rt = 0; rt < 2; ++rt)
#pragma unroll
      for (int s = 0; s < 2; ++s) {
        const float* p = zf + offR[rt] + kc * BK + s * 32 + quad * 8;
        a32[buf][rt][s][0] = ((const float4*)p)[0];
        a32[buf][rt][s][1] = ((const float4*)p)[1];
      }
  };
  auto cvtA = [&](int buf) {
#pragma unroll
    for (int rt = 0; rt < 2; ++rt)
#pragma unroll
      for (int s = 0; s < 2; ++s) {
        float4 lo = a32[buf][rt][s][0], hi = a32[buf][rt][s][1];
        short8 r;
        r[0] = (short)f2bf(lo.x); r[1] = (short)f2bf(lo.y);
        r[2] = (short)f2bf(lo.z); r[3] = (short)f2bf(lo.w);
        r[4] = (short)f2bf(hi.x); r[5] = (short)f2bf(hi.y);
        r[6] = (short)f2bf(hi.z); r[7] = (short)f2bf(hi.w);
        aB[buf][rt][s] = r;
      }
  };
  auto stageB = [&](int kch, u16* dst) {
#pragma unroll
    for (int t = 0; t < 4; ++t)
      gl2lds16(pB + (size_t)t * 8 * KDIM + kch * BK, dst + t * 8 * BK);
  };

  stageB(kb, lBw0);
  loadA(0, 0);
  asm volatile("s_waitcnt vmcnt(0)" ::: "memory");
  cvtA(0);
  __builtin_amdgcn_s_barrier();

#pragma unroll
  for (int kc = 0; kc < 4; ++kc) {
    const int cur = kc & 1, nxt = cur ^ 1;
    if (kc < 3) {
      stageB(kb + kc + 1, nxt ? lBw1 : lBw0);
      loadA(kc + 1, nxt);
    }
#pragma unroll
    for (int s = 0; s < 2; ++s) {
      const int sl = s * 4 + quad;
      __builtin_amdgcn_s_setprio(1);
#pragma unroll
      for (int ct = 0; ct < 8; ++ct) {
        short8 bF = *(const short8*)
            &lB[cur][(ct * 16 + colid) * BK + ((sl ^ csw) * 8)];
        acc[0][ct] = __builtin_amdgcn_mfma_f32_16x16x32_bf16(
            aB[cur][0][s], bF, acc[0][ct], 0, 0, 0);
        acc[1][ct] = __builtin_amdgcn_mfma_f32_16x16x32_bf16(
            aB[cur][1][s], bF, acc[1][ct], 0, 0, 0);
      }
      __builtin_amdgcn_s_setprio(0);
    }
    if (kc < 3) {
      asm volatile("s_waitcnt vmcnt(0)" ::: "memory");
      cvtA(nxt);
      __builtin_amdgcn_s_barrier();
    }
  }

  float b1v[8];
#pragma unroll
  for (int ct = 0; ct < 8; ++ct)
    b1v[ct] = isV ? 0.f : b1[n0 + ct * 16 + colid];
#pragma unroll
  for (int rt = 0; rt < 2; ++rt)
#pragma unroll
    for (int j = 0; j < 4; ++j) {
      int r = r0 + wid * 32 + rt * 16 + quad * 4 + j;
      if (r < NR) {
#pragma unroll
        for (int ct = 0; ct < 8; ++ct)
          Oh[(size_t)r * HDIM + n0 + ct * 16 + colid] =
              f2h(acc[rt][ct][j] + b1v[ct]);
      }
    }
}

// Edge pass over sorted packed perm. Contiguous 256-edge range per block,
// bijective XCD swizzle (m204): each XCD owns a contiguous slab of the
// sorted order -> its U slab (~3.2MB) stays in its private 4MB L2.
__global__ __launch_bounds__(256, 8) void edge_kernel_sorted(
    const u16* __restrict__ U, const u16* __restrict__ V,
    const int4* __restrict__ perm4,
    const float* __restrict__ w2, const float* __restrict__ b2,
    float* __restrict__ out, int E) {
  const int tid  = threadIdx.x;
  const int lane = tid & 63;
  const int wid  = tid >> 6;
  const int li   = lane & 7;
  const int eg   = lane >> 3;

  float w2v[32];
#pragma unroll
  for (int i = 0; i < 32; ++i) w2v[i] = w2[li * 32 + i];
  const float b2v = b2[0];

  // m204 bijective XCD swizzle -> contiguous slab per XCD.
  const int nwg = gridDim.x;
  const int q = nwg >> 3, r = nwg & 7;
  const int xcd = blockIdx.x & 7, sub = blockIdx.x >> 3;
  const int swz = (xcd < r ? xcd * (q + 1) : r * (q + 1) + (xcd - r) * q) + sub;
  const int base0 = swz * 256;

#pragma unroll
  for (int it = 0; it < 8; ++it) {
    const int idx = base0 + it * 32 + wid * 8 + eg;
    const int ii  = min(idx, E - 1);
    const int4 rc = perm4[ii];                   // {row, col, e}
    const short8* up = (const short8*)(U + (size_t)rc.x * HDIM + li * 32);
    const short8* vp = (const short8*)(V + (size_t)rc.y * HDIM + li * 32);
    short8 ub[4], vb[4];
#pragma unroll
    for (int t = 0; t < 4; ++t) { ub[t] = up[t]; vb[t] = vp[t]; }
    float s = 0.f;
#pragma unroll
    for (int t = 0; t < 4; ++t)
#pragma unroll
      for (int i = 0; i < 8; ++i) {
        float h = h2f((u16)ub[t][i]) + h2f((u16)vb[t][i]);
        s += fmaxf(h, 0.f) * w2v[t * 8 + i];
      }
    s += __shfl_xor(s, 1, 8);
    s += __shfl_xor(s, 2, 8);
    s += __shfl_xor(s, 4, 8);
    if (li == 0 && idx < E) out[rc.z] = s + b2v;
  }
}

// Plain (unsorted) edge pass — used when ws can't fit the sort buffers.
__global__ __launch_bounds__(256, 8) void edge_kernel(
    const u16* __restrict__ U, const u16* __restrict__ V,
    const int* __restrict__ row, const int* __restrict__ col,
    const float* __restrict__ w2, const float* __restrict__ b2,
    float* __restrict__ out, int E) {
  const int tid  = threadIdx.x;
  const int lane = tid & 63;
  const int wid  = tid >> 6;
  const int li   = lane & 7;
  const int eg   = lane >> 3;
  float w2v[32];
#pragma unroll
  for (int i = 0; i < 32; ++i) w2v[i] = w2[li * 32 + i];
  const float b2v = b2[0];
  for (int base = blockIdx.x * 32; base < E; base += gridDim.x * 32) {
    const int e  = base + wid * 8 + eg;
    const int ee = min(e, E - 1);
    const short8* up = (const short8*)(U + (size_t)row[ee] * HDIM + li * 32);
    const short8* vp = (const short8*)(V + (size_t)col[ee] * HDIM + li * 32);
    short8 ub[4], vb[4];
#pragma unroll
    for (int t = 0; t < 4; ++t) { ub[t] = up[t]; vb[t] = vp[t]; }
    float s = 0.f;
#pragma unroll
    for (int t = 0; t < 4; ++t)
#pragma unroll
      for (int i = 0; i < 8; ++i) {
        float h = h2f((u16)ub[t][i]) + h2f((u16)vb[t][i]);
        s += fmaxf(h, 0.f) * w2v[t * 8 + i];
      }
    s += __shfl_xor(s, 1, 8);
    s += __shfl_xor(s, 2, 8);
    s += __shfl_xor(s, 4, 8);
    if (li == 0 && e < E) out[e] = s + b2v;
  }
}

// Correct-but-slow fp32 fallback (only if ws too small): 16 edges/block.
__global__ void fallback_kernel(
    const float* __restrict__ zd, const float* __restrict__ zt,
    const int* __restrict__ row, const int* __restrict__ col,
    const float* __restrict__ W1, const float* __restrict__ b1,
    const float* __restrict__ W2, const float* __restrict__ b2,
    float* __restrict__ out, int E) {
  __shared__ float zc[16][512];
  __shared__ float red[4][16];
  const int e0 = blockIdx.x * 16;
  const int tid = threadIdx.x;
  for (int i = tid; i < 16 * 512; i += 256) {
    int e = i >> 9, k = i & 511;
    int ge = min(e0 + e, E - 1);
    zc[e][k] = (k < HDIM) ? zd[(size_t)row[ge] * HDIM + k]
                          : zt[(size_t)col[ge] * HDIM + (k - HDIM)];
  }
  __syncthreads();
  float acc[16];
#pragma unroll
  for (int e = 0; e < 16; ++e) acc[e] = 0.f;
  for (int k = 0; k < KDIM; ++k) {
    float w = W1[k * HDIM + tid];
#pragma unroll
    for (int e = 0; e < 16; ++e) acc[e] += zc[e][k] * w;
  }
  float wv = W2[tid], bv = b1[tid];
  const int lane = tid & 63, wid = tid >> 6;
#pragma unroll
  for (int e = 0; e < 16; ++e) {
    float pv = fmaxf(acc[e] + bv, 0.f) * wv;
#pragma unroll
    for (int off = 32; off >= 1; off >>= 1) pv += __shfl_down(pv, off, 64);
    if (lane == 0) red[wid][e] = pv;
  }
  __syncthreads();
  if (tid < 16) {
    int ge = e0 + tid;
    if (ge < E)
      out[ge] = red[0][tid] + red[1][tid] + red[2][tid] + red[3][tid] + b2[0];
  }
}

static inline size_t align256(size_t x) { return (x + 255) & ~(size_t)255; }

extern "C" void kernel_launch(void* const* d_in, const int* in_sizes, int n_in,
                              void* d_out, int out_size, void* d_ws, size_t ws_size,
                              hipStream_t stream) {
  const float* zd_f = (const float*)d_in[0];
  const float* zt_f = (const float*)d_in[1];
  const int*   row  = (const int*)d_in[2];
  const int*   col  = (const int*)d_in[3];
  const float* W1   = (const float*)d_in[4];
  const float* b1   = (const float*)d_in[5];
  const float* W2   = (const float*)d_in[6];
  const float* b2   = (const float*)d_in[7];
  float* out = (float*)d_out;

  const int E  = in_sizes[2];            // 500000
  const int ND = in_sizes[0] / HDIM;     // 50000
  const int NT = in_sizes[1] / HDIM;     // 20000
  const int NB = (ND + (1 << BIN_SHIFT) - 1) >> BIN_SHIFT;  // 3125

  size_t off_w1t = 0;                                             // 256KB
  size_t off_U   = align256((size_t)KDIM * HDIM * sizeof(u16));
  size_t off_V   = align256(off_U + (size_t)ND * HDIM * sizeof(u16));
  size_t off_b2d = align256(off_V + (size_t)NT * HDIM * sizeof(u16));
  size_t off_cur = align256(off_b2d + (size_t)NHIST * NB * sizeof(int));
  size_t off_pm  = align256(off_cur + (size_t)NB * sizeof(int));
  size_t need_sorted = off_pm + (size_t)E * sizeof(int4);         // ~44.9MB
  size_t need_plain  = off_b2d;                                   // ~36.1MB

  if (ws_size >= need_plain) {
    u16* w1t = (u16*)((char*)d_ws + off_w1t);
    u16* Uh  = (u16*)((char*)d_ws + off_U);
    u16* Vh  = (u16*)((char*)d_ws + off_V);
    const int nUb = ((ND + 127) / 128) * 2;    // 782
    const int nVb = ((NT + 127) / 128) * 2;    // 314

    if (ws_size >= need_sorted && NB <= 3200) {
      int*  bins2d = (int*)((char*)d_ws + off_b2d);
      int*  cursor = (int*)((char*)d_ws + off_cur);
      int4* perm4  = (int4*)((char*)d_ws + off_pm);
      prep_hist<<<32 + NHIST, 256, 0, stream>>>(W1, w1t, row, bins2d, E, NB);
      scan_kernel<<<1, 256, 0, stream>>>(bins2d, cursor, NB);
      scatter_kernel<<<256, 256, 0, stream>>>(row, col, cursor, perm4, E);
      uv_gemm<<<nUb + nVb, 256, 0, stream>>>(zd_f, zt_f, w1t, b1, Uh, Vh,
                                             ND, NT, nUb);
      const int nwg = (E + 255) / 256;         // 1954 blocks, 256 edges each
      edge_kernel_sorted<<<nwg, 256, 0, stream>>>(Uh, Vh, perm4, W2, b2,
                                                  out, E);
    } else {
      prep_hist<<<32, 256, 0, stream>>>(W1, w1t, row, (int*)nullptr, 0, NB);
      uv_gemm<<<nUb + nVb, 256, 0, stream>>>(zd_f, zt_f, w1t, b1, Uh, Vh,
                                             ND, NT, nUb);
      int egrid = (E + 31) / 32;
      if (egrid > 2048) egrid = 2048;
      edge_kernel<<<egrid, 256, 0, stream>>>(Uh, Vh, row, col, W2, b2,
                                             out, E);
    }
  } else {
    fallback_kernel<<<(E + 15) / 16, 256, 0, stream>>>(
        zd_f, zt_f, row, col, W1, b1, W2, b2, out, E);
  }
}

// Round 13
// 251.673 us; speedup vs baseline: 1.3062x; 1.3062x over previous
//
#include <hip/hip_runtime.h>
#include <hip/hip_bf16.h>
#include <stdint.h>

// EdgeDecoder: out = relu(concat(zd[row], zt[col]) @ W1 + b1) @ W2 + b2
// R15: U/V split + COARSE 8-bin row binning (one scatter kernel, ~15us)
// replacing R13/R14's fine sort (~110us of hist/scan/scatter). Each XCD
// processes one bin -> its U slab (~3.2MB) lives in its private 4MB L2
// (edge pass measured 88us / FETCH 193MB in R14 with this locality).
//  - scatter8: fixed-capacity bin regions, LDS-aggregated ranks, 8 global
//    cursor atomics per block-iter; perm packed int2{row|col<<16, e}.
//  - edge pass: bin = blockIdx&7 (XCD round-robin), grid-stride in-bin.
//  - uv_gemm: R13's full-width variant (verified in R13; z read once).

typedef unsigned short u16;
typedef __attribute__((ext_vector_type(8))) short short8;
typedef __attribute__((ext_vector_type(4))) float f32x4;

#define HDIM 256
#define KDIM 512
#define BK 64
#define BINCAP 66560   // E/8 + ~17 sigma slack (row uniform over ND)

__device__ __forceinline__ u16 f2bf(float f) {
  union { float f; uint32_t u; } v; v.f = f;
  uint32_t u = v.u;
  return (u16)((u + 0x7fffu + ((u >> 16) & 1u)) >> 16);   // RNE, inputs finite
}
__device__ __forceinline__ u16 f2h(float f) {
  union { _Float16 h; u16 u; } v; v.h = (_Float16)f;      // v_cvt_f16_f32 RNE
  return v.u;
}
__device__ __forceinline__ float h2f(u16 b) {
  union { _Float16 h; u16 u; } v; v.u = b;
  return (float)v.h;
}

// async global->LDS, 16B per lane; LDS dest must be wave-uniform base (+lane*16)
__device__ __forceinline__ void gl2lds16(const void* g, void* l) {
  __builtin_amdgcn_global_load_lds(
      (const __attribute__((address_space(1))) unsigned int*)g,
      (__attribute__((address_space(3))) unsigned int*)l,
      16, 0, 0);
}

// Prep: 64x64 LDS-tiled transpose of W1 (512x256 fp32 -> 256x512 bf16).
__global__ void prep_w1t(const float* __restrict__ w1, u16* __restrict__ w1t) {
  const int b = blockIdx.x;
  __shared__ float tile[64][65];
  const int k0 = (b >> 2) * 64, n0 = (b & 3) * 64;
  const int tx = threadIdx.x & 63, ty = threadIdx.x >> 6;
#pragma unroll
  for (int i = ty; i < 64; i += 4)
    tile[i][tx] = w1[(size_t)(k0 + i) * HDIM + n0 + tx];
  __syncthreads();
#pragma unroll
  for (int i = ty; i < 64; i += 4)
    w1t[(size_t)(n0 + i) * KDIM + k0 + tx] = f2bf(tile[tx][i]);
}

// Coarse 8-bin scatter: bin = min(7, row*8/ND). Block-aggregated ranks in
// LDS, 8 global cursor atomics per block-iteration, fixed bin regions.
__global__ __launch_bounds__(256) void scatter8(
    const int* __restrict__ row, const int* __restrict__ col,
    int* __restrict__ cursors, int2* __restrict__ perm,
    int E, float binScale) {
  __shared__ int lcnt[8], lbase[8];
  for (int e0 = blockIdx.x * 256; e0 < E; e0 += gridDim.x * 256) {
    const int e = e0 + threadIdx.x;
    const bool v = (e < E);
    int r = 0, c = 0, bin = 0, rank = 0;
    if (threadIdx.x < 8) lcnt[threadIdx.x] = 0;
    __syncthreads();
    if (v) {
      r = row[e]; c = col[e];
      bin = min(7, (int)((float)r * binScale));
      rank = atomicAdd(&lcnt[bin], 1);            // LDS atomic (fast)
    }
    __syncthreads();
    if (threadIdx.x < 8)
      lbase[threadIdx.x] = atomicAdd(&cursors[threadIdx.x], lcnt[threadIdx.x]);
    __syncthreads();
    if (v) {
      int pos = lbase[bin] + rank;                // overflow prob ~0 (17 sigma)
      perm[(size_t)bin * BINCAP + pos] = make_int2(r | (c << 16), e);
    }
  }
}

// UV GEMM full-width (R13-verified): blocks [0,nUb) U = zd@W1d (+b1 folded),
// rest V = zt@W1t. Block = 128 rows x 256 cols, wave = 32 rows x 256 cols,
// acc[2][16]; A from sequential fp32 z rows cvt in-reg (dbuf); B gl2lds+XOR.
__global__ __launch_bounds__(256, 2) void uv_gemm(
    const float* __restrict__ zdf, const float* __restrict__ ztf,
    const u16* __restrict__ w1t, const float* __restrict__ b1,
    u16* __restrict__ Uh, u16* __restrict__ Vh,
    int ND, int NT, int nUb) {
  __shared__ u16 lB[2][HDIM * BK];   // 2 x 32KB [n][k], XOR-swizzled

  const int bid = blockIdx.x;
  const int isV = (bid >= nUb);
  const int lb  = isV ? (bid - nUb) : bid;
  const float* zf = isV ? ztf : zdf;
  u16* Oh = isV ? Vh : Uh;
  const int NR = isV ? NT : ND;
  const int r0 = lb * 128;
  const int kb = isV ? 4 : 0;

  const int tid   = threadIdx.x;
  const int wid   = tid >> 6;
  const int lane  = tid & 63;
  const int r8    = lane >> 3;
  const int slog  = ((lane & 7) ^ (r8 & 7)) * 8;   // inv-swizzled src piece
  const int colid = lane & 15;
  const int quad  = lane >> 4;
  const int csw   = colid & 7;

  const u16* pB = w1t + (uint32_t)(wid * 64 + r8) * KDIM + slog;
  u16* lBw0 = &lB[0][(wid * 64) * BK];
  u16* lBw1 = &lB[1][(wid * 64) * BK];

  uint32_t offR[2];
#pragma unroll
  for (int rt = 0; rt < 2; ++rt) {
    int r = min(r0 + wid * 32 + rt * 16 + colid, NR - 1);
    offR[rt] = (uint32_t)r * HDIM;
  }

  f32x4 acc[2][16];
#pragma unroll
  for (int i = 0; i < 2; ++i)
#pragma unroll
    for (int j = 0; j < 16; ++j) acc[i][j] = f32x4{0.f, 0.f, 0.f, 0.f};

  float4 a32[2][2][2];   // in-flight fp32 A [rt][s][half]
  short8 aB[2][2][2];    // [buf][rt][s] bf16 fragments

  auto loadA = [&](int kc) {
#pragma unroll
    for (int rt = 0; rt < 2; ++rt)
#pragma unroll
      for (int s = 0; s < 2; ++s) {
        const float* p = zf + offR[rt] + kc * BK + s * 32 + quad * 8;
        a32[rt][s][0] = ((const float4*)p)[0];
        a32[rt][s][1] = ((const float4*)p)[1];
      }
  };
  auto cvtA = [&](int buf) {
#pragma unroll
    for (int rt = 0; rt < 2; ++rt)
#pragma unroll
      for (int s = 0; s < 2; ++s) {
        float4 lo = a32[rt][s][0], hi = a32[rt][s][1];
        short8 r;
        r[0] = (short)f2bf(lo.x); r[1] = (short)f2bf(lo.y);
        r[2] = (short)f2bf(lo.z); r[3] = (short)f2bf(lo.w);
        r[4] = (short)f2bf(hi.x); r[5] = (short)f2bf(hi.y);
        r[6] = (short)f2bf(hi.z); r[7] = (short)f2bf(hi.w);
        aB[buf][rt][s] = r;
      }
  };
  auto stageB = [&](int kch, u16* dst) {
#pragma unroll
    for (int t = 0; t < 8; ++t)
      gl2lds16(pB + (size_t)t * 8 * KDIM + kch * BK, dst + t * 8 * BK);
  };

  loadA(0);
  stageB(kb, lBw0);
  asm volatile("s_waitcnt vmcnt(0)" ::: "memory");
  cvtA(0);
  __builtin_amdgcn_s_barrier();

#pragma unroll
  for (int kc = 0; kc < 4; ++kc) {
    const int cur = kc & 1, nxt = cur ^ 1;
    if (kc < 3) {
      loadA(kc + 1);
      stageB(kb + kc + 1, nxt ? lBw1 : lBw0);
    }
#pragma unroll
    for (int s = 0; s < 2; ++s) {
      const int sl = s * 4 + quad;
      __builtin_amdgcn_s_setprio(1);
#pragma unroll
      for (int ct = 0; ct < 16; ++ct) {
        short8 bF = *(const short8*)
            &lB[cur][(ct * 16 + colid) * BK + ((sl ^ csw) * 8)];
        acc[0][ct] = __builtin_amdgcn_mfma_f32_16x16x32_bf16(
            aB[cur][0][s], bF, acc[0][ct], 0, 0, 0);
        acc[1][ct] = __builtin_amdgcn_mfma_f32_16x16x32_bf16(
            aB[cur][1][s], bF, acc[1][ct], 0, 0, 0);
      }
      __builtin_amdgcn_s_setprio(0);
    }
    if (kc < 3) {
      asm volatile("s_waitcnt vmcnt(0)" ::: "memory");
      cvtA(nxt);
      __builtin_amdgcn_s_barrier();
    }
  }

  float b1v[16];
#pragma unroll
  for (int ct = 0; ct < 16; ++ct)
    b1v[ct] = isV ? 0.f : b1[ct * 16 + colid];
#pragma unroll
  for (int rt = 0; rt < 2; ++rt)
#pragma unroll
    for (int j = 0; j < 4; ++j) {
      int r = r0 + wid * 32 + rt * 16 + quad * 4 + j;
      if (r < NR) {
#pragma unroll
        for (int ct = 0; ct < 16; ++ct)
          Oh[(size_t)r * HDIM + ct * 16 + colid] =
              f2h(acc[rt][ct][j] + b1v[ct]);
      }
    }
}

// Edge pass over binned perm. bin = blockIdx&7 (XCD round-robin) -> each
// XCD's U slab (~3.2MB) stays in its private L2. 8 lanes/edge, lane li owns
// cols [li*32,+32); perm record is one sequential 8B read.
__global__ __launch_bounds__(256, 8) void edge_kernel_bins(
    const u16* __restrict__ U, const u16* __restrict__ V,
    const int2* __restrict__ perm, const int* __restrict__ cnt,
    const float* __restrict__ w2, const float* __restrict__ b2,
    float* __restrict__ out) {
  const int tid  = threadIdx.x;
  const int lane = tid & 63;
  const int wid  = tid >> 6;
  const int li   = lane & 7;
  const int eg   = lane >> 3;
  const int bin  = blockIdx.x & 7;
  const int sub  = blockIdx.x >> 3;
  const int nsub = gridDim.x >> 3;

  float w2v[32];
#pragma unroll
  for (int i = 0; i < 32; ++i) w2v[i] = w2[li * 32 + i];
  const float b2v = b2[0];

  const int n = cnt[bin];
  const int2* p = perm + (size_t)bin * BINCAP;

  for (int base = sub * 32; base < n; base += nsub * 32) {
    const int idx = base + wid * 8 + eg;
    const int ii  = min(idx, n - 1);
    const int2 rc = p[ii];                       // {row|col<<16, e}
    const int r = rc.x & 0xFFFF;
    const int c = ((unsigned)rc.x) >> 16;
    const short8* up = (const short8*)(U + (size_t)r * HDIM + li * 32);
    const short8* vp = (const short8*)(V + (size_t)c * HDIM + li * 32);
    short8 ub[4], vb[4];
#pragma unroll
    for (int t = 0; t < 4; ++t) { ub[t] = up[t]; vb[t] = vp[t]; }
    float s = 0.f;
#pragma unroll
    for (int t = 0; t < 4; ++t)
#pragma unroll
      for (int i = 0; i < 8; ++i) {
        float h = h2f((u16)ub[t][i]) + h2f((u16)vb[t][i]);
        s += fmaxf(h, 0.f) * w2v[t * 8 + i];
      }
    s += __shfl_xor(s, 1, 8);
    s += __shfl_xor(s, 2, 8);
    s += __shfl_xor(s, 4, 8);
    if (li == 0 && idx < n) out[rc.y] = s + b2v;
  }
}

// Plain (unsorted) edge pass — used when ws can't fit the bin buffers.
__global__ __launch_bounds__(256, 8) void edge_kernel(
    const u16* __restrict__ U, const u16* __restrict__ V,
    const int* __restrict__ row, const int* __restrict__ col,
    const float* __restrict__ w2, const float* __restrict__ b2,
    float* __restrict__ out, int E) {
  const int tid  = threadIdx.x;
  const int lane = tid & 63;
  const int wid  = tid >> 6;
  const int li   = lane & 7;
  const int eg   = lane >> 3;
  float w2v[32];
#pragma unroll
  for (int i = 0; i < 32; ++i) w2v[i] = w2[li * 32 + i];
  const float b2v = b2[0];
  for (int base = blockIdx.x * 32; base < E; base += gridDim.x * 32) {
    const int e  = base + wid * 8 + eg;
    const int ee = min(e, E - 1);
    const short8* up = (const short8*)(U + (size_t)row[ee] * HDIM + li * 32);
    const short8* vp = (const short8*)(V + (size_t)col[ee] * HDIM + li * 32);
    short8 ub[4], vb[4];
#pragma unroll
    for (int t = 0; t < 4; ++t) { ub[t] = up[t]; vb[t] = vp[t]; }
    float s = 0.f;
#pragma unroll
    for (int t = 0; t < 4; ++t)
#pragma unroll
      for (int i = 0; i < 8; ++i) {
        float h = h2f((u16)ub[t][i]) + h2f((u16)vb[t][i]);
        s += fmaxf(h, 0.f) * w2v[t * 8 + i];
      }
    s += __shfl_xor(s, 1, 8);
    s += __shfl_xor(s, 2, 8);
    s += __shfl_xor(s, 4, 8);
    if (li == 0 && e < E) out[e] = s + b2v;
  }
}

// Correct-but-slow fp32 fallback (only if ws too small): 16 edges/block.
__global__ void fallback_kernel(
    const float* __restrict__ zd, const float* __restrict__ zt,
    const int* __restrict__ row, const int* __restrict__ col,
    const float* __restrict__ W1, const float* __restrict__ b1,
    const float* __restrict__ W2, const float* __restrict__ b2,
    float* __restrict__ out, int E) {
  __shared__ float zc[16][512];
  __shared__ float red[4][16];
  const int e0 = blockIdx.x * 16;
  const int tid = threadIdx.x;
  for (int i = tid; i < 16 * 512; i += 256) {
    int e = i >> 9, k = i & 511;
    int ge = min(e0 + e, E - 1);
    zc[e][k] = (k < HDIM) ? zd[(size_t)row[ge] * HDIM + k]
                          : zt[(size_t)col[ge] * HDIM + (k - HDIM)];
  }
  __syncthreads();
  float acc[16];
#pragma unroll
  for (int e = 0; e < 16; ++e) acc[e] = 0.f;
  for (int k = 0; k < KDIM; ++k) {
    float w = W1[k * HDIM + tid];
#pragma unroll
    for (int e = 0; e < 16; ++e) acc[e] += zc[e][k] * w;
  }
  float wv = W2[tid], bv = b1[tid];
  const int lane = tid & 63, wid = tid >> 6;
#pragma unroll
  for (int e = 0; e < 16; ++e) {
    float pv = fmaxf(acc[e] + bv, 0.f) * wv;
#pragma unroll
    for (int off = 32; off >= 1; off >>= 1) pv += __shfl_down(pv, off, 64);
    if (lane == 0) red[wid][e] = pv;
  }
  __syncthreads();
  if (tid < 16) {
    int ge = e0 + tid;
    if (ge < E)
      out[ge] = red[0][tid] + red[1][tid] + red[2][tid] + red[3][tid] + b2[0];
  }
}

static inline size_t align256(size_t x) { return (x + 255) & ~(size_t)255; }

extern "C" void kernel_launch(void* const* d_in, const int* in_sizes, int n_in,
                              void* d_out, int out_size, void* d_ws, size_t ws_size,
                              hipStream_t stream) {
  const float* zd_f = (const float*)d_in[0];
  const float* zt_f = (const float*)d_in[1];
  const int*   row  = (const int*)d_in[2];
  const int*   col  = (const int*)d_in[3];
  const float* W1   = (const float*)d_in[4];
  const float* b1   = (const float*)d_in[5];
  const float* W2   = (const float*)d_in[6];
  const float* b2   = (const float*)d_in[7];
  float* out = (float*)d_out;

  const int E  = in_sizes[2];            // 500000
  const int ND = in_sizes[0] / HDIM;     // 50000
  const int NT = in_sizes[1] / HDIM;     // 20000

  size_t off_w1t = 0;                                             // 256KB
  size_t off_U   = align256((size_t)KDIM * HDIM * sizeof(u16));
  size_t off_V   = align256(off_U + (size_t)ND * HDIM * sizeof(u16));
  size_t off_cur = align256(off_V + (size_t)NT * HDIM * sizeof(u16));
  size_t off_pm  = align256(off_cur + 8 * sizeof(int));
  size_t need_bins  = off_pm + (size_t)8 * BINCAP * sizeof(int2);  // ~40.4MB
  size_t need_plain = off_cur;                                     // ~36.1MB

  // fp16 tables can hold row/col in 16 bits each? (packing requirement)
  const bool packOK = (ND <= 65536) && (NT <= 65536) && (E <= 8 * BINCAP);

  if (ws_size >= need_plain) {
    u16* w1t = (u16*)((char*)d_ws + off_w1t);
    u16* Uh  = (u16*)((char*)d_ws + off_U);
    u16* Vh  = (u16*)((char*)d_ws + off_V);
    const int nUb = (ND + 127) / 128;    // 391
    const int nVb = (NT + 127) / 128;    // 157
    prep_w1t<<<32, 256, 0, stream>>>(W1, w1t);

    if (ws_size >= need_bins && packOK) {
      int*  cursors = (int*)((char*)d_ws + off_cur);
      int2* perm    = (int2*)((char*)d_ws + off_pm);
      hipMemsetAsync(cursors, 0, 8 * sizeof(int), stream);
      scatter8<<<512, 256, 0, stream>>>(row, col, cursors, perm, E,
                                        8.0f / (float)ND);
      uv_gemm<<<nUb + nVb, 256, 0, stream>>>(zd_f, zt_f, w1t, b1, Uh, Vh,
                                             ND, NT, nUb);
      edge_kernel_bins<<<2048, 256, 0, stream>>>(Uh, Vh, perm, cursors,
                                                 W2, b2, out);
    } else {
      uv_gemm<<<nUb + nVb, 256, 0, stream>>>(zd_f, zt_f, w1t, b1, Uh, Vh,
                                             ND, NT, nUb);
      int egrid = (E + 31) / 32;
      if (egrid > 2048) egrid = 2048;
      edge_kernel<<<egrid, 256, 0, stream>>>(Uh, Vh, row, col, W2, b2,
                                             out, E);
    }
  } else {
    fallback_kernel<<<(E + 15) / 16, 256, 0, stream>>>(
        zd_f, zt_f, row, col, W1, b1, W2, b2, out, E);
  }
}